// Round 12
// baseline (331.148 us; speedup 1.0000x reference)
//
#include <hip/hip_runtime.h>
#include <hip/hip_bf16.h>

#define B_DIM 16384
#define P_DIM 4096
#define D_DIM 256
#define BK 32
#define NSTEP (D_DIM / BK)   // 8

typedef float f32x4 __attribute__((ext_vector_type(4)));
typedef __bf16 bf16x8 __attribute__((ext_vector_type(8)));

__device__ __forceinline__ unsigned short f2bf_rne(float f) {
  unsigned int u = __builtin_bit_cast(unsigned int, f);
  u += 0x7fffu + ((u >> 16) & 1u);
  return (unsigned short)(u >> 16);
}

__global__ __launch_bounds__(256) void prep_kernel(
    const float* __restrict__ x, const float* __restrict__ p,
    unsigned short* __restrict__ xb, unsigned short* __restrict__ pb,
    float* __restrict__ xsq, float* __restrict__ psq) {
  int row  = blockIdx.x * 4 + (threadIdx.x >> 6);
  int lane = threadIdx.x & 63;
  const float4* src;
  unsigned short* dst;
  float* sq;
  if (row < B_DIM) {
    src = (const float4*)(x + (size_t)row * D_DIM);
    dst = xb + (size_t)row * D_DIM;
    sq  = xsq + row;
  } else {
    int r = row - B_DIM;
    src = (const float4*)(p + (size_t)r * D_DIM);
    dst = pb + (size_t)r * D_DIM;
    sq  = psq + r;
  }
  float4 v = src[lane];
  ushort4 o;
  o.x = f2bf_rne(v.x); o.y = f2bf_rne(v.y);
  o.z = f2bf_rne(v.z); o.w = f2bf_rne(v.w);
  ((ushort4*)dst)[lane] = o;
  float s = v.x * v.x + v.y * v.y + v.z * v.z + v.w * v.w;
  #pragma unroll
  for (int off = 32; off > 0; off >>= 1) s += __shfl_down(s, off);
  if (lane == 0) *sq = s;
}

__device__ __forceinline__ void async16(const unsigned short* g, const void* l) {
  __builtin_amdgcn_global_load_lds(
      (const __attribute__((address_space(1))) void*)g,
      (__attribute__((address_space(3))) void*)l,
      16, 0, 0);
}

// DIAG 1: write-only. Exact R10 epilogue store pattern (grid/occupancy/
// addresses identical), trivial values, 6 reps. Later overwritten by the
// real GEMM. Isolates the output-stream cost.
__global__ __launch_bounds__(256, 3) void wdiag(
    const float* __restrict__ xsq, const float* __restrict__ psq,
    float* __restrict__ out) {
  const int tid  = threadIdx.x;
  const int w    = tid >> 6;
  const int lane = tid & 63;
  const int bid  = blockIdx.x;
  const int swz = (bid & 7) * 512 + (bid >> 3);
  const int bm  = swz >> 5;
  const int bn  = swz & 31;
  const int wr = w >> 1, wc = w & 1;
  const int arowB = bm * 128 + wr * 64;
  const int browB = bn * 128 + wc * 64;
  const int rl = lane & 15, hL = lane >> 4;

  f32x4 ps[4];
  #pragma unroll
  for (int n = 0; n < 4; ++n)
    ps[n] = *(const f32x4*)(psq + browB + n * 16 + hL * 4);

  #pragma unroll 1
  for (int rep = 0; rep < 6; ++rep) {
    #pragma unroll
    for (int m = 0; m < 4; ++m) {
      const float xs = xsq[arowB + m * 16 + rl] + (float)rep;
      float* orow = out + (size_t)(arowB + m * 16 + rl) * P_DIM + browB + hL * 4;
      #pragma unroll
      for (int n = 0; n < 4; ++n) {
        f32x4 v;
        #pragma unroll
        for (int j = 0; j < 4; ++j) v[j] = xs + ps[n][j];
        *(f32x4*)(orow + n * 16) = v;
      }
    }
    asm volatile("" ::: "memory");   // keep all reps' stores
  }
}

// DIAG 2: read+compute only. Exact R10 K-loop (staging, vmcnt, barriers,
// MFMA); epilogue replaced by a 4B/thread sink into d_ws. 2 reps.
__global__ __launch_bounds__(256, 3) void rdiag(
    const unsigned short* __restrict__ A,
    const unsigned short* __restrict__ Bm,
    const float* __restrict__ xsq, const float* __restrict__ psq,
    float* __restrict__ sink) {
  __shared__ __align__(16) char lds[3][2][8192];
  const int tid  = threadIdx.x;
  const int lane = tid & 63;
  const int bid  = blockIdx.x;
  const int swz = (bid & 7) * 512 + (bid >> 3);
  const int bm  = swz >> 5;
  const int bn  = swz & 31;

  const int trow = tid >> 2;
  const int tcol = (((tid & 3) ^ (trow & 3)) << 3);
  const unsigned short* aSrc = A  + (size_t)(bm * 128 + trow) * D_DIM + tcol;
  const unsigned short* bSrc = Bm + (size_t)(bn * 128 + trow) * D_DIM + tcol;
  const int ldst = tid * 16;

#define STAGE(bufi, ktE) do { _Pragma("unroll")                                \
    for (int i = 0; i < 2; ++i) {                                              \
      async16(aSrc + (size_t)i * 64 * D_DIM + (ktE),                           \
              (const void*)(&lds[bufi][0][0] + i * 4096 + ldst));              \
      async16(bSrc + (size_t)i * 64 * D_DIM + (ktE),                           \
              (const void*)(&lds[bufi][1][0] + i * 4096 + ldst));              \
    } } while (0)

  const int w  = tid >> 6;
  const int wr = w >> 1, wc = w & 1;
  const int arow = wr * 64 + (lane & 15);
  const int brow = wc * 64 + (lane & 15);
  const int koff = (((lane >> 4) ^ (lane & 3)) << 4);

  float ssum = 0.0f;
  #pragma unroll 1
  for (int rep = 0; rep < 2; ++rep) {
    asm volatile("s_waitcnt vmcnt(0)" ::: "memory");
    __builtin_amdgcn_s_barrier();
    __builtin_amdgcn_sched_barrier(0);

    f32x4 acc[4][4];
    #pragma unroll
    for (int m = 0; m < 4; ++m)
      #pragma unroll
      for (int n = 0; n < 4; ++n) acc[m][n] = 0.0f;

    STAGE(0, 0);
    STAGE(1, BK);

    #pragma unroll
    for (int t = 0; t < NSTEP; ++t) {
      if (t < NSTEP - 1) asm volatile("s_waitcnt vmcnt(4)" ::: "memory");
      else               asm volatile("s_waitcnt vmcnt(0)" ::: "memory");
      __builtin_amdgcn_s_barrier();
      __builtin_amdgcn_sched_barrier(0);
      if (t < NSTEP - 2) STAGE((t + 2) % 3, (t + 2) * BK);
      const char* La = &lds[t % 3][0][0];
      const char* Lb = &lds[t % 3][1][0];
      bf16x8 av[4], bv[4];
      #pragma unroll
      for (int m = 0; m < 4; ++m)
        av[m] = *(const bf16x8*)(La + (arow + m * 16) * 64 + koff);
      #pragma unroll
      for (int n = 0; n < 4; ++n)
        bv[n] = *(const bf16x8*)(Lb + (brow + n * 16) * 64 + koff);
      #pragma unroll
      for (int m = 0; m < 4; ++m)
        #pragma unroll
        for (int n = 0; n < 4; ++n)
          acc[m][n] = __builtin_amdgcn_mfma_f32_16x16x32_bf16(bv[n], av[m], acc[m][n], 0, 0, 0);
    }
    #pragma unroll
    for (int m = 0; m < 4; ++m)
      #pragma unroll
      for (int n = 0; n < 4; ++n)
        ssum += acc[m][n][0] + acc[m][n][1] + acc[m][n][2] + acc[m][n][3];
  }
  sink[(size_t)bid * 256 + tid] = ssum;
#undef STAGE
}

// Real GEMM: identical to R10 (128x128, 4 waves, triple-buffer depth-2).
__global__ __launch_bounds__(256, 3) void dist_gemm(
    const unsigned short* __restrict__ A,
    const unsigned short* __restrict__ Bm,
    const float* __restrict__ xsq, const float* __restrict__ psq,
    float* __restrict__ out) {
  __shared__ __align__(16) char lds[3][2][8192];
  const int tid  = threadIdx.x;
  const int w    = tid >> 6;
  const int lane = tid & 63;
  const int bid  = blockIdx.x;
  const int swz = (bid & 7) * 512 + (bid >> 3);
  const int bm  = swz >> 5;
  const int bn  = swz & 31;
  const int wr = w >> 1, wc = w & 1;

  const int trow = tid >> 2;
  const int tcol = (((tid & 3) ^ (trow & 3)) << 3);
  const unsigned short* aSrc = A  + (size_t)(bm * 128 + trow) * D_DIM + tcol;
  const unsigned short* bSrc = Bm + (size_t)(bn * 128 + trow) * D_DIM + tcol;
  const int ldst = tid * 16;

#define STAGE(bufi, ktE) do { _Pragma("unroll")                                \
    for (int i = 0; i < 2; ++i) {                                              \
      async16(aSrc + (size_t)i * 64 * D_DIM + (ktE),                           \
              (const void*)(&lds[bufi][0][0] + i * 4096 + ldst));              \
      async16(bSrc + (size_t)i * 64 * D_DIM + (ktE),                           \
              (const void*)(&lds[bufi][1][0] + i * 4096 + ldst));              \
    } } while (0)

  const int arow = wr * 64 + (lane & 15);
  const int brow = wc * 64 + (lane & 15);
  const int koff = (((lane >> 4) ^ (lane & 3)) << 4);

  f32x4 acc[4][4];
  #pragma unroll
  for (int m = 0; m < 4; ++m)
    #pragma unroll
    for (int n = 0; n < 4; ++n) acc[m][n] = 0.0f;

  STAGE(0, 0);
  STAGE(1, BK);

  #pragma unroll
  for (int t = 0; t < NSTEP; ++t) {
    if (t < NSTEP - 1) asm volatile("s_waitcnt vmcnt(4)" ::: "memory");
    else               asm volatile("s_waitcnt vmcnt(0)" ::: "memory");
    __builtin_amdgcn_s_barrier();
    __builtin_amdgcn_sched_barrier(0);
    if (t < NSTEP - 2) STAGE((t + 2) % 3, (t + 2) * BK);
    const char* La = &lds[t % 3][0][0];
    const char* Lb = &lds[t % 3][1][0];
    bf16x8 av[4], bv[4];
    #pragma unroll
    for (int m = 0; m < 4; ++m)
      av[m] = *(const bf16x8*)(La + (arow + m * 16) * 64 + koff);
    #pragma unroll
    for (int n = 0; n < 4; ++n)
      bv[n] = *(const bf16x8*)(Lb + (brow + n * 16) * 64 + koff);
    #pragma unroll
    for (int m = 0; m < 4; ++m)
      #pragma unroll
      for (int n = 0; n < 4; ++n)
        acc[m][n] = __builtin_amdgcn_mfma_f32_16x16x32_bf16(bv[n], av[m], acc[m][n], 0, 0, 0);
  }

  const int xrowB = bm * 128 + wr * 64;
  const int pcolB = bn * 128 + wc * 64;
  const int rL = lane & 15;
  const int hL = lane >> 4;
  f32x4 ps[4];
  #pragma unroll
  for (int n = 0; n < 4; ++n)
    ps[n] = *(const f32x4*)(psq + pcolB + n * 16 + hL * 4);
  #pragma unroll
  for (int m = 0; m < 4; ++m) {
    const float xs = xsq[xrowB + m * 16 + rL];
    float* orow = out + (size_t)(xrowB + m * 16 + rL) * P_DIM + pcolB + hL * 4;
    #pragma unroll
    for (int n = 0; n < 4; ++n) {
      f32x4 v;
      #pragma unroll
      for (int j = 0; j < 4; ++j) {
        float d = fmaf(-2.0f, acc[m][n][j], xs + ps[n][j]);
        v[j] = __builtin_sqrtf(fmaxf(d, 0.0f));
      }
      *(f32x4*)(orow + n * 16) = v;
    }
  }
#undef STAGE
}

extern "C" void kernel_launch(void* const* d_in, const int* in_sizes, int n_in,
                              void* d_out, int out_size, void* d_ws, size_t ws_size,
                              hipStream_t stream) {
  const float* x = (const float*)d_in[0];
  const float* p = (const float*)d_in[1];
  float* out = (float*)d_out;

  char* ws = (char*)d_ws;
  unsigned short* xb = (unsigned short*)ws;                                // 8 MB
  unsigned short* pb = (unsigned short*)(ws + (size_t)B_DIM * D_DIM * 2);  // 2 MB
  float* xsq = (float*)(ws + (size_t)(B_DIM + P_DIM) * D_DIM * 2);
  float* psq = xsq + B_DIM;
  float* sink = (float*)(ws + (size_t)64 * 1024 * 1024);                   // 4 MB @64MB

  prep_kernel<<<(B_DIM + P_DIM) / 4, 256, 0, stream>>>(x, p, xb, pb, xsq, psq);

  // DIAG 1: isolated write stream (6 reps), later overwritten.
  wdiag<<<4096, 256, 0, stream>>>(xsq, psq, out);
  // DIAG 2: isolated read+compute (2 reps), sink to ws.
  rdiag<<<4096, 256, 0, stream>>>(xb, pb, xsq, psq, sink);

  // Real GEMM (R10 structure) -> correct output.
  dist_gemm<<<(B_DIM / 128) * (P_DIM / 128), 256, 0, stream>>>(xb, pb, xsq, psq, out);
}